// Round 6
// baseline (223.912 us; speedup 1.0000x reference)
//
#include <hip/hip_runtime.h>
#include <math.h>

#define B_SZ   4
#define N_SEQ  197
#define DIMC   2048
#define HEADS  32
#define HD     64
#define WIN    8
#define M_ROWS (B_SZ * N_SEQ)   // 788
#define M_PAD  896               // 14 * 64

using f32x4 = __attribute__((ext_vector_type(4))) float;
using s16x8 = __attribute__((ext_vector_type(8))) short;

__device__ inline ushort f2bf(float f) {
  uint x = __float_as_uint(f);
  uint r = (x + 0x7fffu + ((x >> 16) & 1u)) >> 16;  // RNE
  return (ushort)r;
}
__device__ inline float bf2f(ushort u) {
  return __uint_as_float(((uint)u) << 16);
}
__device__ inline s16x8 pack8(f32x4 a, f32x4 b) {
  s16x8 r;
  r[0] = (short)f2bf(a.x); r[1] = (short)f2bf(a.y);
  r[2] = (short)f2bf(a.z); r[3] = (short)f2bf(a.w);
  r[4] = (short)f2bf(b.x); r[5] = (short)f2bf(b.y);
  r[6] = (short)f2bf(b.z); r[7] = (short)f2bf(b.w);
  return r;
}

// ---------------- zero-init kernel (for atomic accumulation) ----------------
__global__ __launch_bounds__(256)
void zero_f32(float* __restrict__ p, int n4) {
  int i = blockIdx.x * 256 + threadIdx.x;
  int stride = gridDim.x * 256;
  for (int j = i; j < n4; j += stride)
    ((f32x4*)p)[j] = (f32x4){0.f, 0.f, 0.f, 0.f};
}

// ---- GEMM, fp32 inputs, in-loop bf16 convert, 64x128 tile, BK=64 -----------
// C = A(fp32, MxK) @ Bw(fp32, NxK)^T. A row index clamped (pad rows read
// garbage, their outputs are never stored). One raw s_barrier per K-step;
// global loads for tile t+1 stay in flight across it (counted-wait idea).
// LDS XOR swizzle (col8 ^ ((row&7)<<3)) applied on BOTH ds_write and ds_read.
// OUT_ATOMIC=0: bf16 store. OUT_ATOMIC=1: fp32 atomicAdd (+bias at z==0).
template<int OUT_ATOMIC>
__global__ __launch_bounds__(256, 3)
void gemm_f32(const float* __restrict__ A, const float* __restrict__ Bw,
              void* __restrict__ Cout, const float* __restrict__ bias,
              int Mdim, int Ndim, int Kfull, int Ksplit) {
  __shared__ ushort As[2][64 * 64];
  __shared__ ushort Bs[2][128 * 64];
  const int tid  = threadIdx.x;
  const int lane = tid & 63;
  const int wave = tid >> 6;

  // XCD-aware bijective swizzle within z-slice (nwg % 8 == 0)
  const int nwg  = gridDim.x * gridDim.y;
  const int phys = blockIdx.y * gridDim.x + blockIdx.x;
  const int cpx  = nwg >> 3;
  const int lg   = (phys & 7) * cpx + (phys >> 3);
  const int m0 = (lg % gridDim.x) * 64;
  const int n0 = (lg / gridDim.x) * 128;
  const int koff = blockIdx.z * Ksplit;

  const int wr = (wave >> 1) * 32;   // wave sub-tile: 32 x 64
  const int wc = (wave & 1) * 64;
  const int fr = lane & 15;
  const int kg = lane >> 4;

  // fragment read columns (ushort idx in a 64-elem row), kk = 0,1
  const int csw0 = (kg * 8)      ^ ((fr & 7) << 3);
  const int csw1 = (32 + kg * 8) ^ ((fr & 7) << 3);

  // staging assignment: A 64x64 (2 granules/thread), B 128x64 (4/thread)
  const int arow = tid >> 2;
  const int agc  = (tid & 3) * 2;
  const int brow = tid >> 1;
  const int bgc  = (tid & 1) * 4;
  const int aidx0 = arow * 64 + (( agc      * 8) ^ ((arow & 7) << 3));
  const int aidx1 = arow * 64 + (((agc + 1) * 8) ^ ((arow & 7) << 3));
  int bidx[4];
#pragma unroll
  for (int g = 0; g < 4; ++g)
    bidx[g] = brow * 64 + (((bgc + g) * 8) ^ ((brow & 7) << 3));

  int acl = m0 + arow; if (acl > Mdim - 1) acl = Mdim - 1;  // clamp: pad rows
  const float* Ap = A  + (size_t)acl * Kfull + koff + agc * 8;
  const float* Bp = Bw + (size_t)(n0 + brow) * Kfull + koff + bgc * 8;

  f32x4 acc[2][4];
#pragma unroll
  for (int i = 0; i < 2; ++i)
#pragma unroll
    for (int j = 0; j < 4; ++j)
      acc[i][j] = (f32x4){0.f, 0.f, 0.f, 0.f};

  f32x4 ra[4], rb[8];
  auto LOADG = [&](int t) {
    const int k = t << 6;
#pragma unroll
    for (int g = 0; g < 4; ++g) ra[g] = *(const f32x4*)(Ap + k + g * 4);
#pragma unroll
    for (int g = 0; g < 8; ++g) rb[g] = *(const f32x4*)(Bp + k + g * 4);
  };
  auto DSWRITE = [&](int buf) {
    *(s16x8*)&As[buf][aidx0] = pack8(ra[0], ra[1]);
    *(s16x8*)&As[buf][aidx1] = pack8(ra[2], ra[3]);
#pragma unroll
    for (int g = 0; g < 4; ++g)
      *(s16x8*)&Bs[buf][bidx[g]] = pack8(rb[2 * g], rb[2 * g + 1]);
  };

  const int nt = Ksplit >> 6;
  LOADG(0);

  for (int t = 0; t < nt; ++t) {
    const int cur = t & 1;
    DSWRITE(cur);                 // compiler inserts counted vmcnt per use
    if (t + 1 < nt) LOADG(t + 1); // issue next tile; stays in flight past bar
    asm volatile("s_waitcnt lgkmcnt(0)" ::: "memory");  // ds_writes complete
    __builtin_amdgcn_s_barrier();
    __builtin_amdgcn_sched_barrier(0);

    s16x8 af0[2], af1[2], bf0[4], bf1[4];
#pragma unroll
    for (int mi = 0; mi < 2; ++mi) {
      const int r = (wr + mi * 16 + fr) * 64;
      af0[mi] = *(const s16x8*)&As[cur][r + csw0];
      af1[mi] = *(const s16x8*)&As[cur][r + csw1];
    }
#pragma unroll
    for (int j = 0; j < 4; ++j) {
      const int r = (wc + j * 16 + fr) * 64;
      bf0[j] = *(const s16x8*)&Bs[cur][r + csw0];
      bf1[j] = *(const s16x8*)&Bs[cur][r + csw1];
    }
#pragma unroll
    for (int mi = 0; mi < 2; ++mi)
#pragma unroll
      for (int j = 0; j < 4; ++j) {
        acc[mi][j] = __builtin_amdgcn_mfma_f32_16x16x32_bf16(af0[mi], bf0[j], acc[mi][j], 0, 0, 0);
        acc[mi][j] = __builtin_amdgcn_mfma_f32_16x16x32_bf16(af1[mi], bf1[j], acc[mi][j], 0, 0, 0);
      }
  }

  // C/D layout: col = lane&15, row = (lane>>4)*4 + reg
  const int crow_base = m0 + wr + kg * 4;
  const int ccol_base = n0 + wc + fr;
  if constexpr (OUT_ATOMIC) {
    float* C = (float*)Cout;
    const bool addb = (bias != nullptr) && (blockIdx.z == 0);
#pragma unroll
    for (int j = 0; j < 4; ++j) {
      int col = ccol_base + j * 16;
      float bv = addb ? bias[col] : 0.f;
#pragma unroll
      for (int mi = 0; mi < 2; ++mi)
#pragma unroll
        for (int r = 0; r < 4; ++r) {
          int grow = crow_base + mi * 16 + r;
          if (grow < Mdim) atomicAdd(&C[(size_t)grow * Ndim + col], acc[mi][j][r] + bv);
        }
    }
  } else {
    ushort* C = (ushort*)Cout;
#pragma unroll
    for (int j = 0; j < 4; ++j) {
      int col = ccol_base + j * 16;
#pragma unroll
      for (int mi = 0; mi < 2; ++mi)
#pragma unroll
        for (int r = 0; r < 4; ++r) {
          int grow = crow_base + mi * 16 + r;
          if (grow < Mdim) C[(size_t)grow * Ndim + col] = f2bf(acc[mi][j][r]);
        }
    }
  }
}

// ---------------- Local attention: one wave per (b, i, h) -------------------
// qkv bf16 (788 x 6144); output ao fp32 (row-major 788 x 2048)
__global__ __launch_bounds__(256)
void local_attn(const ushort* __restrict__ qkv, float* __restrict__ ao) {
  const int gw = blockIdx.x * 4 + (threadIdx.x >> 6);
  if (gw >= B_SZ * HEADS * N_SEQ) return;
  const int lane = threadIdx.x & 63;
  const int h = gw % HEADS;
  const int t = gw / HEADS;
  const int i = t % N_SEQ;
  const int b = t / N_SEQ;
  const int row = b * N_SEQ + i;
  const size_t stride = 3 * DIMC;

  const float q = bf2f(qkv[(size_t)row * stride + h * HD + lane]) * 0.125f;
  int j0 = i - WIN; if (j0 < 0) j0 = 0;
  int j1 = i + WIN; if (j1 > N_SEQ) j1 = N_SEQ;

  float s[16];
#pragma unroll
  for (int jj = 0; jj < 16; ++jj) {
    int j = j0 + jj;
    bool ok = (j < j1);
    int jc = ok ? j : (j1 - 1);
    float kd = bf2f(qkv[(size_t)(b * N_SEQ + jc) * stride + DIMC + h * HD + lane]);
    float p = q * kd;
#pragma unroll
    for (int o = 32; o > 0; o >>= 1) p += __shfl_xor(p, o);
    float d = fabsf((float)(i - j));
    float m = 1.0f - d * 0.0625f;
    s[jj] = ok ? p * m : -INFINITY;
  }

  float mx = -INFINITY;
#pragma unroll
  for (int jj = 0; jj < 16; ++jj) mx = fmaxf(mx, s[jj]);
  float sum = 0.f;
#pragma unroll
  for (int jj = 0; jj < 16; ++jj) { float e = expf(s[jj] - mx); s[jj] = e; sum += e; }
  const float inv = 1.f / sum;

  float o = 0.f;
#pragma unroll
  for (int jj = 0; jj < 16; ++jj) {
    int j = j0 + jj;
    if (j < j1)
      o += s[jj] * bf2f(qkv[(size_t)(b * N_SEQ + j) * stride + 2 * DIMC + h * HD + lane]);
  }
  ao[(size_t)row * DIMC + h * HD + lane] = o * inv;
}

// ----------------------------------------------------------------------------
extern "C" void kernel_launch(void* const* d_in, const int* in_sizes, int n_in,
                              void* d_out, int out_size, void* d_ws, size_t ws_size,
                              hipStream_t stream) {
  const float* x      = (const float*)d_in[0];
  const float* qkv_w  = (const float*)d_in[1];
  const float* proj_w = (const float*)d_in[2];
  const float* proj_b = (const float*)d_in[3];
  float* out = (float*)d_out;

  // ws: qkv bf16 (788 x 6144), ao fp32 (M_PAD x 2048; pad rows hold poison,
  // proj reads them via clamped/unstored paths only)
  char* p = (char*)d_ws;
  ushort* qkv_bf = (ushort*)p;  p += (((size_t)M_ROWS * 3 * DIMC * 2 + 255) & ~(size_t)255);
  float*  ao_f   = (float*)p;

  dim3 blk(256);

  // zero d_out (proj accumulates atomically)
  zero_f32<<<dim3(512), blk, 0, stream>>>(out, M_ROWS * DIMC / 4);

  // QKV GEMM: (788x2048) @ (6144x2048)^T -> bf16; grid (14,48) = 672 blocks
  gemm_f32<0><<<dim3(M_PAD / 64, (3 * DIMC) / 128, 1), blk, 0, stream>>>(
      x, qkv_w, (void*)qkv_bf, nullptr, M_ROWS, 3 * DIMC, DIMC, DIMC);

  // Local attention -> ao fp32
  int total_waves = B_SZ * HEADS * N_SEQ;  // 25216
  local_attn<<<dim3((total_waves + 3) / 4), blk, 0, stream>>>(qkv_bf, ao_f);

  // Proj GEMM: split-K=4, grid (14,16,4) = 896 blocks, atomics + bias@z0
  gemm_f32<1><<<dim3(M_PAD / 64, DIMC / 128, 4), blk, 0, stream>>>(
      ao_f, proj_w, (void*)out, proj_b, M_ROWS, DIMC, DIMC, DIMC / 4);
}

// Round 7
// 138.727 us; speedup vs baseline: 1.6140x; 1.6140x over previous
//
#include <hip/hip_runtime.h>
#include <math.h>

#define B_SZ   4
#define N_SEQ  197
#define DIMC   2048
#define HEADS  32
#define HD     64
#define WIN    8
#define M_ROWS (B_SZ * N_SEQ)   // 788
#define M_PAD  896               // 14 * 64

using f32x4 = __attribute__((ext_vector_type(4))) float;
using s16x8 = __attribute__((ext_vector_type(8))) short;

__device__ inline ushort f2bf(float f) {
  uint x = __float_as_uint(f);
  uint r = (x + 0x7fffu + ((x >> 16) & 1u)) >> 16;  // RNE
  return (ushort)r;
}
__device__ inline float bf2f(ushort u) {
  return __uint_as_float(((uint)u) << 16);
}

__device__ inline void gload16(const ushort* g, ushort* l) {
  __builtin_amdgcn_global_load_lds(
      (const __attribute__((address_space(1))) unsigned int*)g,
      (__attribute__((address_space(3))) unsigned int*)l, 16, 0, 0);
}

// ---- fused fp32->bf16 conversion (x, qkv_w, proj_w) + zero d_out -----------
#define NX (M_ROWS * DIMC / 8)        // 201728
#define NQ (3 * DIMC * DIMC / 8)      // 1572864
#define NP (DIMC * DIMC / 8)          // 524288
#define NZ (M_ROWS * DIMC / 8)        // 201728 (zero range, 8 floats/thread)

__global__ __launch_bounds__(256)
void cvt_all(const float* __restrict__ x,  const float* __restrict__ qw,
             const float* __restrict__ pw, ushort* __restrict__ xb,
             ushort* __restrict__ qwb, ushort* __restrict__ pwb,
             float* __restrict__ outz) {
  int i = blockIdx.x * 256 + threadIdx.x;
  const float* src; ushort* dst; int idx;
  if (i < NX)                { src = x;  dst = xb;  idx = i; }
  else if (i < NX + NQ)      { src = qw; dst = qwb; idx = i - NX; }
  else if (i < NX + NQ + NP) { src = pw; dst = pwb; idx = i - NX - NQ; }
  else if (i < NX + NQ + NP + NZ) {
    int z = i - NX - NQ - NP;
    ((f32x4*)outz)[2 * z]     = (f32x4){0.f, 0.f, 0.f, 0.f};
    ((f32x4*)outz)[2 * z + 1] = (f32x4){0.f, 0.f, 0.f, 0.f};
    return;
  } else return;
  f32x4 a = ((const f32x4*)src)[2 * idx];
  f32x4 b = ((const f32x4*)src)[2 * idx + 1];
  ushort4 u0, u1;
  u0.x = f2bf(a.x); u0.y = f2bf(a.y); u0.z = f2bf(a.z); u0.w = f2bf(a.w);
  u1.x = f2bf(b.x); u1.y = f2bf(b.y); u1.z = f2bf(b.z); u1.w = f2bf(b.w);
  ((ushort4*)dst)[2 * idx]     = u0;
  ((ushort4*)dst)[2 * idx + 1] = u1;
}

// ---- GEMM: C = A(bf16, MxK) @ Bw(bf16, NxK)^T, 64x128 tile, BK=32 ----------
// Depth-3 counted-vmcnt pipeline over 4 LDS buffers (3 loads/wave/tile;
// steady-state vmcnt(6) leaves 2 tiles in flight across the barrier).
// 2-way slot swizzle: source col pre-swizzled, read slot XOR-matched.
// OUT_ATOMIC=0: bf16 store. OUT_ATOMIC=1: fp32 atomicAdd (+bias at z==0).
template<int OUT_ATOMIC>
__global__ __launch_bounds__(256, 3)
void gemm_bt_bf16(const ushort* __restrict__ A, const ushort* __restrict__ Bw,
                  void* __restrict__ Cout, const float* __restrict__ bias,
                  int Mdim, int Ndim, int Kfull, int Ksplit) {
  __shared__ ushort As[4][64 * 32];    // 16 KB
  __shared__ ushort Bs[4][128 * 32];   // 32 KB
  const int tid  = threadIdx.x;
  const int lane = tid & 63;
  const int wave = tid >> 6;

  // XCD-aware bijective swizzle within z-slice (nwg % 8 == 0)
  const int nwg  = gridDim.x * gridDim.y;
  const int phys = blockIdx.y * gridDim.x + blockIdx.x;
  const int cpx  = nwg >> 3;
  const int lg   = (phys & 7) * cpx + (phys >> 3);
  const int m0 = (lg % gridDim.x) * 64;
  const int n0 = (lg / gridDim.x) * 128;
  const int koff = blockIdx.z * Ksplit;

  const int wr = (wave >> 1) * 32;   // wave sub-tile: 32 x 64
  const int wc = (wave & 1) * 64;
  const int fr = lane & 15;
  const int kg = lane >> 4;
  const int srow = lane >> 2;                            // row in 16-row chunk
  const int scol = ((lane & 3) ^ ((srow >> 1) & 3)) * 8; // pre-swizzled src slot
  const int rdA  = (kg ^ ((fr >> 1) & 3)) * 8;           // matching read slot

  f32x4 acc[2][4];
#pragma unroll
  for (int i = 0; i < 2; ++i)
#pragma unroll
    for (int j = 0; j < 4; ++j)
      acc[i][j] = (f32x4){0.f, 0.f, 0.f, 0.f};

  const ushort* Asrc0 = A  + (size_t)(m0 + wave * 16 + srow)      * Kfull + koff + scol;
  const ushort* Bsrc0 = Bw + (size_t)(n0 + wave * 32 + srow)      * Kfull + koff + scol;
  const ushort* Bsrc1 = Bw + (size_t)(n0 + wave * 32 + 16 + srow) * Kfull + koff + scol;

  const int nt = Ksplit >> 5;   // >= 16 always here

  auto STAGE = [&](int kk, int b) {
    const int k = kk << 5;
    gload16(Asrc0 + k, &As[b][wave * 512]);
    gload16(Bsrc0 + k, &Bs[b][wave * 1024]);
    gload16(Bsrc1 + k, &Bs[b][wave * 1024 + 512]);
  };

  // prologue: tiles 0..2 in flight (9 loads/wave outstanding)
  STAGE(0, 0);
  STAGE(1, 1);
  STAGE(2, 2);

  for (int t = 0; t < nt; ++t) {
    // wait only for tile t's own 3 loads; deeper tiles stay in flight
    const int rem = nt - 1 - t;
    if (rem >= 2)      asm volatile("s_waitcnt vmcnt(6)" ::: "memory");
    else if (rem == 1) asm volatile("s_waitcnt vmcnt(3)" ::: "memory");
    else               asm volatile("s_waitcnt vmcnt(0)" ::: "memory");
    __builtin_amdgcn_s_barrier();
    __builtin_amdgcn_sched_barrier(0);

    if (t + 3 < nt) STAGE(t + 3, (t + 3) & 3);

    const int cur = t & 3;
    s16x8 af[2], bfr[4];
#pragma unroll
    for (int mi = 0; mi < 2; ++mi)
      af[mi] = *(const s16x8*)(&As[cur][(wr + mi * 16 + fr) * 32 + rdA]);
#pragma unroll
    for (int j = 0; j < 4; ++j)
      bfr[j] = *(const s16x8*)(&Bs[cur][(wc + j * 16 + fr) * 32 + rdA]);
    __builtin_amdgcn_s_setprio(1);
#pragma unroll
    for (int mi = 0; mi < 2; ++mi)
#pragma unroll
      for (int j = 0; j < 4; ++j)
        acc[mi][j] = __builtin_amdgcn_mfma_f32_16x16x32_bf16(af[mi], bfr[j], acc[mi][j], 0, 0, 0);
    __builtin_amdgcn_s_setprio(0);
  }

  // C/D layout: col = lane&15, row = (lane>>4)*4 + reg
  const int crow_base = m0 + wr + kg * 4;
  const int ccol_base = n0 + wc + fr;
  if constexpr (OUT_ATOMIC) {
    float* C = (float*)Cout;
    const bool addb = (bias != nullptr) && (blockIdx.z == 0);
#pragma unroll
    for (int j = 0; j < 4; ++j) {
      int col = ccol_base + j * 16;
      float bv = addb ? bias[col] : 0.f;
#pragma unroll
      for (int mi = 0; mi < 2; ++mi)
#pragma unroll
        for (int r = 0; r < 4; ++r) {
          int grow = crow_base + mi * 16 + r;
          if (grow < Mdim) atomicAdd(&C[(size_t)grow * Ndim + col], acc[mi][j][r] + bv);
        }
    }
  } else {
    ushort* C = (ushort*)Cout;
#pragma unroll
    for (int j = 0; j < 4; ++j) {
      int col = ccol_base + j * 16;
#pragma unroll
      for (int mi = 0; mi < 2; ++mi)
#pragma unroll
        for (int r = 0; r < 4; ++r) {
          int grow = crow_base + mi * 16 + r;
          if (grow < Mdim) C[(size_t)grow * Ndim + col] = f2bf(acc[mi][j][r]);
        }
    }
  }
}

// ---------------- Local attention: one wave per (b, i, h) -------------------
// qkv bf16 (788 x 6144) -> ao bf16 (788 x 2048)
__global__ __launch_bounds__(256)
void local_attn(const ushort* __restrict__ qkv, ushort* __restrict__ ao) {
  const int gw = blockIdx.x * 4 + (threadIdx.x >> 6);
  if (gw >= B_SZ * HEADS * N_SEQ) return;
  const int lane = threadIdx.x & 63;
  const int h = gw % HEADS;
  const int t = gw / HEADS;
  const int i = t % N_SEQ;
  const int b = t / N_SEQ;
  const int row = b * N_SEQ + i;
  const size_t stride = 3 * DIMC;

  const float q = bf2f(qkv[(size_t)row * stride + h * HD + lane]) * 0.125f;
  int j0 = i - WIN; if (j0 < 0) j0 = 0;
  int j1 = i + WIN; if (j1 > N_SEQ) j1 = N_SEQ;

  float s[16];
#pragma unroll
  for (int jj = 0; jj < 16; ++jj) {
    int j = j0 + jj;
    bool ok = (j < j1);
    int jc = ok ? j : (j1 - 1);
    float kd = bf2f(qkv[(size_t)(b * N_SEQ + jc) * stride + DIMC + h * HD + lane]);
    float p = q * kd;
#pragma unroll
    for (int o = 32; o > 0; o >>= 1) p += __shfl_xor(p, o);
    float d = fabsf((float)(i - j));
    float m = 1.0f - d * 0.0625f;
    s[jj] = ok ? p * m : -INFINITY;
  }

  float mx = -INFINITY;
#pragma unroll
  for (int jj = 0; jj < 16; ++jj) mx = fmaxf(mx, s[jj]);
  float sum = 0.f;
#pragma unroll
  for (int jj = 0; jj < 16; ++jj) { float e = expf(s[jj] - mx); s[jj] = e; sum += e; }
  const float inv = 1.f / sum;

  float o = 0.f;
#pragma unroll
  for (int jj = 0; jj < 16; ++jj) {
    int j = j0 + jj;
    if (j < j1)
      o += s[jj] * bf2f(qkv[(size_t)(b * N_SEQ + j) * stride + 2 * DIMC + h * HD + lane]);
  }
  ao[(size_t)row * DIMC + h * HD + lane] = f2bf(o * inv);
}

// ----------------------------------------------------------------------------
extern "C" void kernel_launch(void* const* d_in, const int* in_sizes, int n_in,
                              void* d_out, int out_size, void* d_ws, size_t ws_size,
                              hipStream_t stream) {
  const float* x      = (const float*)d_in[0];
  const float* qkv_w  = (const float*)d_in[1];
  const float* proj_w = (const float*)d_in[2];
  const float* proj_b = (const float*)d_in[3];
  float* out = (float*)d_out;

  // ws layout (bf16 buffers; pad rows of x_bf / ao_bf hold poison and are
  // only read for pad output rows, whose stores are masked)
  char* p = (char*)d_ws;
  ushort* x_bf    = (ushort*)p;                 p += (size_t)M_PAD * DIMC * 2;
  ushort* qkvw_bf = (ushort*)p;                 p += (size_t)3 * DIMC * DIMC * 2;
  ushort* projw_bf= (ushort*)p;                 p += (size_t)DIMC * DIMC * 2;
  ushort* qkv_bf  = (ushort*)p;                 p += (size_t)M_ROWS * 3 * DIMC * 2;
  ushort* ao_bf   = (ushort*)p;

  dim3 blk(256);

  // conversions + zero d_out (proj accumulates atomically)
  {
    int total = NX + NQ + NP + NZ;
    cvt_all<<<dim3((total + 255) / 256), blk, 0, stream>>>(
        x, qkv_w, proj_w, x_bf, qkvw_bf, projw_bf, out);
  }

  // QKV GEMM: 64x128 tiles, grid (14,48) = 672 blocks, bf16 out
  gemm_bt_bf16<0><<<dim3(M_PAD / 64, (3 * DIMC) / 128, 1), blk, 0, stream>>>(
      x_bf, qkvw_bf, (void*)qkv_bf, nullptr, M_ROWS, 3 * DIMC, DIMC, DIMC);

  // Local attention -> bf16 (788 x 2048)
  int total_waves = B_SZ * HEADS * N_SEQ;  // 25216
  local_attn<<<dim3((total_waves + 3) / 4), blk, 0, stream>>>(qkv_bf, ao_bf);

  // Proj GEMM: 64x128 tiles, split-K=4, grid (14,16,4) = 896 blocks,
  // fp32 atomicAdd into zeroed d_out, bias added by z==0 splits.
  gemm_bt_bf16<1><<<dim3(M_PAD / 64, DIMC / 128, 4), blk, 0, stream>>>(
      ao_bf, projw_bf, (void*)out, proj_b, M_ROWS, DIMC, DIMC, DIMC / 4);
}

// Round 8
// 106.559 us; speedup vs baseline: 2.1013x; 1.3019x over previous
//
#include <hip/hip_runtime.h>
#include <math.h>

#define B_SZ   4
#define N_SEQ  197
#define DIMC   2048
#define HEADS  32
#define HD     64
#define WIN    8
#define M_ROWS (B_SZ * N_SEQ)   // 788
#define M_PAD  896               // 7 * 128

using f32x4 = __attribute__((ext_vector_type(4))) float;
using s16x8 = __attribute__((ext_vector_type(8))) short;

__device__ inline ushort f2bf(float f) {
  uint x = __float_as_uint(f);
  uint r = (x + 0x7fffu + ((x >> 16) & 1u)) >> 16;  // RNE
  return (ushort)r;
}
__device__ inline float bf2f(ushort u) {
  return __uint_as_float(((uint)u) << 16);
}

__device__ inline void gload16(const ushort* g, ushort* l) {
  __builtin_amdgcn_global_load_lds(
      (const __attribute__((address_space(1))) unsigned int*)g,
      (__attribute__((address_space(3))) unsigned int*)l, 16, 0, 0);
}

// ---------- fused fp32 -> bf16 conversion (x, qkv_w, proj_w) ----------------
#define NX (M_ROWS * DIMC / 8)        // 201728
#define NQ (3 * DIMC * DIMC / 8)      // 1572864
#define NP (DIMC * DIMC / 8)          // 524288

__global__ __launch_bounds__(256)
void cvt_all(const float* __restrict__ x,  const float* __restrict__ qw,
             const float* __restrict__ pw, ushort* __restrict__ xb,
             ushort* __restrict__ qwb, ushort* __restrict__ pwb) {
  int i = blockIdx.x * 256 + threadIdx.x;
  const float* src; ushort* dst; int idx;
  if (i < NX)                { src = x;  dst = xb;  idx = i; }
  else if (i < NX + NQ)      { src = qw; dst = qwb; idx = i - NX; }
  else if (i < NX + NQ + NP) { src = pw; dst = pwb; idx = i - NX - NQ; }
  else return;
  f32x4 a = ((const f32x4*)src)[2 * idx];
  f32x4 b = ((const f32x4*)src)[2 * idx + 1];
  ushort4 u0, u1;
  u0.x = f2bf(a.x); u0.y = f2bf(a.y); u0.z = f2bf(a.z); u0.w = f2bf(a.w);
  u1.x = f2bf(b.x); u1.y = f2bf(b.y); u1.z = f2bf(b.z); u1.w = f2bf(b.w);
  ((ushort4*)dst)[2 * idx]     = u0;
  ((ushort4*)dst)[2 * idx + 1] = u1;
}

// ---- GEMM: Cpart[z] = A(bf16,MxK) @ Bw(bf16,NxK)^T over K-slice z ----------
// 128x128 tile, 4 waves, 64x64 out/wave: 16 MFMA + 8 ds_read_b128 per K-step.
// Depth-2 counted-vmcnt pipeline over 3 LDS buffers (4 loads/wave/tile;
// steady-state vmcnt(4) keeps next tile's loads in flight across s_barrier).
// 2-way slot swizzle (src col pre-swizzled / read XOR-matched). Output:
// bf16 partial slice at Cout + z*Mdim*Ndim (guarded rows < Mdim).
__global__ __launch_bounds__(256, 3)
void gemm_bt_bf16(const ushort* __restrict__ A, const ushort* __restrict__ Bw,
                  ushort* __restrict__ Cout,
                  int Mdim, int Ndim, int Kfull, int Ksplit) {
  __shared__ ushort As[3][128 * 32];   // 3 x 8 KB
  __shared__ ushort Bs[3][128 * 32];   // 3 x 8 KB
  const int tid  = threadIdx.x;
  const int lane = tid & 63;
  const int wave = tid >> 6;

  // XCD-aware bijective swizzle within z-slice (nwg % 8 == 0)
  const int nwg  = gridDim.x * gridDim.y;
  const int phys = blockIdx.y * gridDim.x + blockIdx.x;
  const int cpx  = nwg >> 3;
  const int lg   = (phys & 7) * cpx + (phys >> 3);
  const int m0 = (lg % gridDim.x) * 128;
  const int n0 = (lg / gridDim.x) * 128;
  const int koff = blockIdx.z * Ksplit;
  ushort* C = Cout + (size_t)blockIdx.z * Mdim * Ndim;  // partial slice

  const int wr = (wave >> 1) * 64;   // wave out sub-tile 64x64
  const int wc = (wave & 1) * 64;
  const int fr = lane & 15;
  const int kg = lane >> 4;
  const int srow = lane >> 2;                            // row in 16-row chunk
  const int scol = ((lane & 3) ^ ((srow >> 1) & 3)) * 8; // pre-swizzled src slot
  const int rdA  = (kg ^ ((fr >> 1) & 3)) * 8;           // matching read slot

  f32x4 acc[4][4];
#pragma unroll
  for (int i = 0; i < 4; ++i)
#pragma unroll
    for (int j = 0; j < 4; ++j)
      acc[i][j] = (f32x4){0.f, 0.f, 0.f, 0.f};

  // wave stages A chunks {2w, 2w+1} and B chunks {2w, 2w+1} (16 rows each)
  const ushort* Asrc0 = A  + (size_t)(m0 + wave * 32 + srow)      * Kfull + koff + scol;
  const ushort* Asrc1 = A  + (size_t)(m0 + wave * 32 + 16 + srow) * Kfull + koff + scol;
  const ushort* Bsrc0 = Bw + (size_t)(n0 + wave * 32 + srow)      * Kfull + koff + scol;
  const ushort* Bsrc1 = Bw + (size_t)(n0 + wave * 32 + 16 + srow) * Kfull + koff + scol;

  const int nt = Ksplit >> 5;   // 32 (qkv) / 16 (proj)

  auto STAGE = [&](int kk, int b) {
    const int k = kk << 5;
    gload16(Asrc0 + k, &As[b][wave * 1024]);
    gload16(Asrc1 + k, &As[b][wave * 1024 + 512]);
    gload16(Bsrc0 + k, &Bs[b][wave * 1024]);
    gload16(Bsrc1 + k, &Bs[b][wave * 1024 + 512]);
  };

  // prologue: tiles 0,1 in flight (8 loads/wave outstanding)
  STAGE(0, 0);
  STAGE(1, 1);

  int cur = 0, s2 = 2;   // consume buffer, stage buffer (t+2)%3
  for (int t = 0; t < nt; ++t) {
    // wait only for tile t's own 4 loads; tile t+1's stay in flight
    if (t < nt - 1) asm volatile("s_waitcnt vmcnt(4)" ::: "memory");
    else            asm volatile("s_waitcnt vmcnt(0)" ::: "memory");
    __builtin_amdgcn_s_barrier();
    __builtin_amdgcn_sched_barrier(0);

    if (t + 2 < nt) STAGE(t + 2, s2);

    s16x8 af[4], bfr[4];
#pragma unroll
    for (int i = 0; i < 4; ++i)
      af[i] = *(const s16x8*)(&As[cur][(wr + i * 16 + fr) * 32 + rdA]);
#pragma unroll
    for (int j = 0; j < 4; ++j)
      bfr[j] = *(const s16x8*)(&Bs[cur][(wc + j * 16 + fr) * 32 + rdA]);
    __builtin_amdgcn_s_setprio(1);
#pragma unroll
    for (int i = 0; i < 4; ++i)
#pragma unroll
      for (int j = 0; j < 4; ++j)
        acc[i][j] = __builtin_amdgcn_mfma_f32_16x16x32_bf16(af[i], bfr[j], acc[i][j], 0, 0, 0);
    __builtin_amdgcn_s_setprio(0);

    cur += 1; if (cur >= 3) cur -= 3;
    s2  += 1; if (s2  >= 3) s2  -= 3;
  }

  // C/D layout: col = lane&15, row = (lane>>4)*4 + reg
  const int crow_base = m0 + wr + kg * 4;
  const int ccol_base = n0 + wc + fr;
#pragma unroll
  for (int j = 0; j < 4; ++j) {
    int col = ccol_base + j * 16;
#pragma unroll
    for (int i = 0; i < 4; ++i)
#pragma unroll
      for (int r = 0; r < 4; ++r) {
        int grow = crow_base + i * 16 + r;
        if (grow < Mdim) C[(size_t)grow * Ndim + col] = f2bf(acc[i][j][r]);
      }
  }
}

// ---- Local attention fused with qkv split-K reduce: one wave per (b,i,h) ---
// qkv partials p0,p1: bf16 (788 x 6144) each; q/k/v = f32 sum of slices.
__global__ __launch_bounds__(256)
void local_attn(const ushort* __restrict__ p0, const ushort* __restrict__ p1,
                ushort* __restrict__ ao) {
  const int gw = blockIdx.x * 4 + (threadIdx.x >> 6);
  if (gw >= B_SZ * HEADS * N_SEQ) return;
  const int lane = threadIdx.x & 63;
  const int h = gw % HEADS;
  const int t = gw / HEADS;
  const int i = t % N_SEQ;
  const int b = t / N_SEQ;
  const int row = b * N_SEQ + i;
  const size_t stride = 3 * DIMC;

  const size_t qi = (size_t)row * stride + h * HD + lane;
  const float q = (bf2f(p0[qi]) + bf2f(p1[qi])) * 0.125f;  // fold scale
  int j0 = i - WIN; if (j0 < 0) j0 = 0;
  int j1 = i + WIN; if (j1 > N_SEQ) j1 = N_SEQ;   // [j0, j1)

  float s[16];
#pragma unroll
  for (int jj = 0; jj < 16; ++jj) {
    int j = j0 + jj;
    bool ok = (j < j1);
    int jc = ok ? j : (j1 - 1);
    size_t ki = (size_t)(b * N_SEQ + jc) * stride + DIMC + h * HD + lane;
    float kd = bf2f(p0[ki]) + bf2f(p1[ki]);
    float p = q * kd;
#pragma unroll
    for (int o = 32; o > 0; o >>= 1) p += __shfl_xor(p, o);
    float d = fabsf((float)(i - j));
    float m = 1.0f - d * 0.0625f;    // (W - d/2)/W
    s[jj] = ok ? p * m : -INFINITY;
  }

  float mx = -INFINITY;
#pragma unroll
  for (int jj = 0; jj < 16; ++jj) mx = fmaxf(mx, s[jj]);
  float sum = 0.f;
#pragma unroll
  for (int jj = 0; jj < 16; ++jj) { float e = expf(s[jj] - mx); s[jj] = e; sum += e; }
  const float inv = 1.f / sum;

  float o = 0.f;
#pragma unroll
  for (int jj = 0; jj < 16; ++jj) {
    int j = j0 + jj;
    if (j < j1) {
      size_t vi = (size_t)(b * N_SEQ + j) * stride + 2 * DIMC + h * HD + lane;
      o += s[jj] * (bf2f(p0[vi]) + bf2f(p1[vi]));
    }
  }
  ao[(size_t)row * DIMC + h * HD + lane] = f2bf(o * inv);
}

// ---- proj split-K reduce: out = sum_z parts[z] + bias (fp32) ---------------
#define NR8 (M_ROWS * DIMC / 8)   // 201728
__global__ __launch_bounds__(256)
void reduce4_bias(const ushort* __restrict__ parts, const float* __restrict__ bias,
                  float* __restrict__ out) {
  int i = blockIdx.x * 256 + threadIdx.x;
  if (i >= NR8) return;
  const size_t slice = (size_t)M_ROWS * DIMC;
  float a[8];
#pragma unroll
  for (int e = 0; e < 8; ++e) a[e] = 0.f;
#pragma unroll
  for (int z = 0; z < 4; ++z) {
    s16x8 v = *(const s16x8*)(parts + z * slice + (size_t)i * 8);
#pragma unroll
    for (int e = 0; e < 8; ++e) a[e] += bf2f((ushort)v[e]);
  }
  const int col = (i * 8) & (DIMC - 1);
  f32x4 b0 = *(const f32x4*)(bias + col);
  f32x4 b1 = *(const f32x4*)(bias + col + 4);
  f32x4 o0 = {a[0] + b0.x, a[1] + b0.y, a[2] + b0.z, a[3] + b0.w};
  f32x4 o1 = {a[4] + b1.x, a[5] + b1.y, a[6] + b1.z, a[7] + b1.w};
  ((f32x4*)out)[2 * i]     = o0;
  ((f32x4*)out)[2 * i + 1] = o1;
}

// ----------------------------------------------------------------------------
extern "C" void kernel_launch(void* const* d_in, const int* in_sizes, int n_in,
                              void* d_out, int out_size, void* d_ws, size_t ws_size,
                              hipStream_t stream) {
  const float* x      = (const float*)d_in[0];
  const float* qkv_w  = (const float*)d_in[1];
  const float* proj_w = (const float*)d_in[2];
  const float* proj_b = (const float*)d_in[3];
  float* out = (float*)d_out;

  // ws layout (bf16; pad rows of x_bf/ao_bf hold poison, read only for
  // pad output rows whose stores are masked)
  char* p = (char*)d_ws;
  ushort* x_bf    = (ushort*)p;  p += (size_t)M_PAD * DIMC * 2;            // 3.7 MB
  ushort* qkvw_bf = (ushort*)p;  p += (size_t)3 * DIMC * DIMC * 2;         // 25.2 MB
  ushort* projw_bf= (ushort*)p;  p += (size_t)DIMC * DIMC * 2;             // 8.4 MB
  ushort* qkv_p   = (ushort*)p;  p += (size_t)2 * M_ROWS * 3 * DIMC * 2;   // 19.4 MB
  ushort* ao_bf   = (ushort*)p;  p += (size_t)M_PAD * DIMC * 2;            // 3.7 MB
  ushort* proj_p  = (ushort*)p;                                            // 12.9 MB

  dim3 blk(256);

  // fp32 -> bf16 conversions
  {
    int total = NX + NQ + NP;
    cvt_all<<<dim3((total + 255) / 256), blk, 0, stream>>>(
        x, qkv_w, proj_w, x_bf, qkvw_bf, projw_bf);
  }

  // QKV GEMM: split-K=2, grid (7,48,2) = 672 blocks, bf16 partial slices
  gemm_bt_bf16<<<dim3(M_PAD / 128, (3 * DIMC) / 128, 2), blk, 0, stream>>>(
      x_bf, qkvw_bf, qkv_p, M_ROWS, 3 * DIMC, DIMC, DIMC / 2);

  // Local attention (+ qkv partial reduce) -> ao bf16
  int total_waves = B_SZ * HEADS * N_SEQ;  // 25216
  local_attn<<<dim3((total_waves + 3) / 4), blk, 0, stream>>>(
      qkv_p, qkv_p + (size_t)M_ROWS * 3 * DIMC, ao_bf);

  // Proj GEMM: split-K=4, grid (7,16,4) = 448 blocks, bf16 partial slices
  gemm_bt_bf16<<<dim3(M_PAD / 128, DIMC / 128, 4), blk, 0, stream>>>(
      ao_bf, projw_bf, proj_p, M_ROWS, DIMC, DIMC, DIMC / 4);

  // Reduce 4 proj partials + bias -> fp32 d_out
  reduce4_bias<<<dim3((NR8 + 255) / 256), blk, 0, stream>>>(proj_p, proj_b, out);
}

// Round 9
// 86.902 us; speedup vs baseline: 2.5766x; 1.2262x over previous
//
#include <hip/hip_runtime.h>
#include <math.h>

#define B_SZ   4
#define N_SEQ  197
#define DIMC   2048
#define HEADS  32
#define HD     64
#define WIN    8
#define M_ROWS (B_SZ * N_SEQ)   // 788
#define M_PAD  896               // 7 * 128

using f32x4 = __attribute__((ext_vector_type(4))) float;
using s16x8 = __attribute__((ext_vector_type(8))) short;

__device__ inline ushort f2bf(float f) {
  uint x = __float_as_uint(f);
  uint r = (x + 0x7fffu + ((x >> 16) & 1u)) >> 16;  // RNE
  return (ushort)r;
}
__device__ inline float bf2f(ushort u) {
  return __uint_as_float(((uint)u) << 16);
}

__device__ inline void gload16(const ushort* g, ushort* l) {
  __builtin_amdgcn_global_load_lds(
      (const __attribute__((address_space(1))) unsigned int*)g,
      (__attribute__((address_space(3))) unsigned int*)l, 16, 0, 0);
}

// ---------- fused fp32 -> bf16 conversion (x, qkv_w, proj_w) ----------------
#define NX (M_ROWS * DIMC / 8)        // 201728
#define NQ (3 * DIMC * DIMC / 8)      // 1572864
#define NP (DIMC * DIMC / 8)          // 524288

__global__ __launch_bounds__(256)
void cvt_all(const float* __restrict__ x,  const float* __restrict__ qw,
             const float* __restrict__ pw, ushort* __restrict__ xb,
             ushort* __restrict__ qwb, ushort* __restrict__ pwb) {
  int i = blockIdx.x * 256 + threadIdx.x;
  const float* src; ushort* dst; int idx;
  if (i < NX)                { src = x;  dst = xb;  idx = i; }
  else if (i < NX + NQ)      { src = qw; dst = qwb; idx = i - NX; }
  else if (i < NX + NQ + NP) { src = pw; dst = pwb; idx = i - NX - NQ; }
  else return;
  f32x4 a = ((const f32x4*)src)[2 * idx];
  f32x4 b = ((const f32x4*)src)[2 * idx + 1];
  ushort4 u0, u1;
  u0.x = f2bf(a.x); u0.y = f2bf(a.y); u0.z = f2bf(a.z); u0.w = f2bf(a.w);
  u1.x = f2bf(b.x); u1.y = f2bf(b.y); u1.z = f2bf(b.z); u1.w = f2bf(b.w);
  ((ushort4*)dst)[2 * idx]     = u0;
  ((ushort4*)dst)[2 * idx + 1] = u1;
}

// ---- GEMM: Cpart[z] = A(bf16,MxK) @ Bw(bf16,NxK)^T over K-slice z ----------
// 128x128 tile, 4 waves, 64x64 out/wave: 16 MFMA + 8 ds_read_b128 per K-step.
// Depth-2 counted-vmcnt pipeline over 3 LDS buffers. 2-way slot swizzle.
// Output: bf16 partial slice at Cout + z*Mdim*Ndim (guarded rows < Mdim).
__global__ __launch_bounds__(256, 3)
void gemm_bt_bf16(const ushort* __restrict__ A, const ushort* __restrict__ Bw,
                  ushort* __restrict__ Cout,
                  int Mdim, int Ndim, int Kfull, int Ksplit) {
  __shared__ ushort As[3][128 * 32];
  __shared__ ushort Bs[3][128 * 32];
  const int tid  = threadIdx.x;
  const int lane = tid & 63;
  const int wave = tid >> 6;

  const int nwg  = gridDim.x * gridDim.y;
  const int phys = blockIdx.y * gridDim.x + blockIdx.x;
  const int cpx  = nwg >> 3;
  const int lg   = (phys & 7) * cpx + (phys >> 3);
  const int m0 = (lg % gridDim.x) * 128;
  const int n0 = (lg / gridDim.x) * 128;
  const int koff = blockIdx.z * Ksplit;
  ushort* C = Cout + (size_t)blockIdx.z * Mdim * Ndim;

  const int wr = (wave >> 1) * 64;
  const int wc = (wave & 1) * 64;
  const int fr = lane & 15;
  const int kg = lane >> 4;
  const int srow = lane >> 2;
  const int scol = ((lane & 3) ^ ((srow >> 1) & 3)) * 8;
  const int rdA  = (kg ^ ((fr >> 1) & 3)) * 8;

  f32x4 acc[4][4];
#pragma unroll
  for (int i = 0; i < 4; ++i)
#pragma unroll
    for (int j = 0; j < 4; ++j)
      acc[i][j] = (f32x4){0.f, 0.f, 0.f, 0.f};

  const ushort* Asrc0 = A  + (size_t)(m0 + wave * 32 + srow)      * Kfull + koff + scol;
  const ushort* Asrc1 = A  + (size_t)(m0 + wave * 32 + 16 + srow) * Kfull + koff + scol;
  const ushort* Bsrc0 = Bw + (size_t)(n0 + wave * 32 + srow)      * Kfull + koff + scol;
  const ushort* Bsrc1 = Bw + (size_t)(n0 + wave * 32 + 16 + srow) * Kfull + koff + scol;

  const int nt = Ksplit >> 5;

  auto STAGE = [&](int kk, int b) {
    const int k = kk << 5;
    gload16(Asrc0 + k, &As[b][wave * 1024]);
    gload16(Asrc1 + k, &As[b][wave * 1024 + 512]);
    gload16(Bsrc0 + k, &Bs[b][wave * 1024]);
    gload16(Bsrc1 + k, &Bs[b][wave * 1024 + 512]);
  };

  STAGE(0, 0);
  STAGE(1, 1);

  int cur = 0, s2 = 2;
  for (int t = 0; t < nt; ++t) {
    if (t < nt - 1) asm volatile("s_waitcnt vmcnt(4)" ::: "memory");
    else            asm volatile("s_waitcnt vmcnt(0)" ::: "memory");
    __builtin_amdgcn_s_barrier();
    __builtin_amdgcn_sched_barrier(0);

    if (t + 2 < nt) STAGE(t + 2, s2);

    s16x8 af[4], bfr[4];
#pragma unroll
    for (int i = 0; i < 4; ++i)
      af[i] = *(const s16x8*)(&As[cur][(wr + i * 16 + fr) * 32 + rdA]);
#pragma unroll
    for (int j = 0; j < 4; ++j)
      bfr[j] = *(const s16x8*)(&Bs[cur][(wc + j * 16 + fr) * 32 + rdA]);
    __builtin_amdgcn_s_setprio(1);
#pragma unroll
    for (int i = 0; i < 4; ++i)
#pragma unroll
      for (int j = 0; j < 4; ++j)
        acc[i][j] = __builtin_amdgcn_mfma_f32_16x16x32_bf16(af[i], bfr[j], acc[i][j], 0, 0, 0);
    __builtin_amdgcn_s_setprio(0);

    cur += 1; if (cur >= 3) cur -= 3;
    s2  += 1; if (s2  >= 3) s2  -= 3;
  }

  const int crow_base = m0 + wr + kg * 4;
  const int ccol_base = n0 + wc + fr;
#pragma unroll
  for (int j = 0; j < 4; ++j) {
    int col = ccol_base + j * 16;
#pragma unroll
    for (int i = 0; i < 4; ++i)
#pragma unroll
      for (int r = 0; r < 4; ++r) {
        int grow = crow_base + i * 16 + r;
        if (grow < Mdim) C[(size_t)grow * Ndim + col] = f2bf(acc[i][j][r]);
      }
  }
}

// ---- Local attention + qkv split-K reduce: one wave per (b,i,h) ------------
// Lane mapping: jj = lane>>2 (window pos 0..15), ds = lane&3 (16-dim segment).
// QK: vectorized k loads, 16 FMA + 2 shfl per lane. Softmax: 4+4 shfl
// butterflies over jj bits + one v_exp. PV: e*(v0+v1) on 16-dim segments,
// LDS transpose [16][68], lane=d sums 16 rows.
__global__ __launch_bounds__(256)
void local_attn(const ushort* __restrict__ p0, const ushort* __restrict__ p1,
                ushort* __restrict__ ao) {
  __shared__ float plds[4][16][68];   // 17.4 KB, 16B-aligned rows
  const int wv = threadIdx.x >> 6;
  const int gw = blockIdx.x * 4 + wv;
  if (gw >= B_SZ * HEADS * N_SEQ) return;
  const int lane = threadIdx.x & 63;
  const int jj = lane >> 2;
  const int ds = lane & 3;
  const int h = gw % HEADS;
  const int t = gw / HEADS;
  const int i = t % N_SEQ;
  const int b = t / N_SEQ;
  const int row = b * N_SEQ + i;
  const size_t stride = 3 * DIMC;

  int j0 = i - WIN; if (j0 < 0) j0 = 0;
  int j1 = i + WIN; if (j1 > N_SEQ) j1 = N_SEQ;   // [j0, j1)
  const int j = j0 + jj;
  const bool ok = (j < j1);
  const int jc = ok ? j : (j1 - 1);

  // q segment (16 dims at ds*16), scale folded
  float qs[16];
  {
    const size_t qi = (size_t)row * stride + h * HD + ds * 16;
    s16x8 a0 = *(const s16x8*)(p0 + qi);
    s16x8 a1 = *(const s16x8*)(p0 + qi + 8);
    s16x8 b0 = *(const s16x8*)(p1 + qi);
    s16x8 b1 = *(const s16x8*)(p1 + qi + 8);
#pragma unroll
    for (int e = 0; e < 8; ++e) {
      qs[e]     = (bf2f((ushort)a0[e]) + bf2f((ushort)b0[e])) * 0.125f;
      qs[8 + e] = (bf2f((ushort)a1[e]) + bf2f((ushort)b1[e])) * 0.125f;
    }
  }

  // dot(q, k[jc]) on this lane's segment
  float s;
  {
    const size_t ki = (size_t)(b * N_SEQ + jc) * stride + DIMC + h * HD + ds * 16;
    s16x8 a0 = *(const s16x8*)(p0 + ki);
    s16x8 a1 = *(const s16x8*)(p0 + ki + 8);
    s16x8 b0 = *(const s16x8*)(p1 + ki);
    s16x8 b1 = *(const s16x8*)(p1 + ki + 8);
    float acc = 0.f;
#pragma unroll
    for (int e = 0; e < 8; ++e) {
      acc += qs[e]     * (bf2f((ushort)a0[e]) + bf2f((ushort)b0[e]));
      acc += qs[8 + e] * (bf2f((ushort)a1[e]) + bf2f((ushort)b1[e]));
    }
    s = acc;
  }
  s += __shfl_xor(s, 1);
  s += __shfl_xor(s, 2);     // full dot, replicated across ds

  // mask weight
  {
    float d = fabsf((float)(i - j));
    float m = 1.0f - d * 0.0625f;   // (W - d/2)/W
    s = ok ? s * m : -INFINITY;
  }

  // softmax across jj (lane bits 2..5)
  float mx = s;
  mx = fmaxf(mx, __shfl_xor(mx, 4));
  mx = fmaxf(mx, __shfl_xor(mx, 8));
  mx = fmaxf(mx, __shfl_xor(mx, 16));
  mx = fmaxf(mx, __shfl_xor(mx, 32));
  float e = __expf(s - mx);          // v_exp_f32 path
  float sum = e;
  sum += __shfl_xor(sum, 4);
  sum += __shfl_xor(sum, 8);
  sum += __shfl_xor(sum, 16);
  sum += __shfl_xor(sum, 32);
  const float inv = 1.f / sum;

  // PV: this lane's e * v[jc] segment -> LDS transpose
  {
    const size_t vi = (size_t)(b * N_SEQ + jc) * stride + 2 * DIMC + h * HD + ds * 16;
    s16x8 a0 = *(const s16x8*)(p0 + vi);
    s16x8 a1 = *(const s16x8*)(p0 + vi + 8);
    s16x8 b0 = *(const s16x8*)(p1 + vi);
    s16x8 b1 = *(const s16x8*)(p1 + vi + 8);
    const float ee = ok ? e : 0.f;   // clamped lanes must contribute 0
    f32x4 w0, w1, w2, w3;
#pragma unroll
    for (int g = 0; g < 4; ++g) {
      w0[g] = ee * (bf2f((ushort)a0[g])     + bf2f((ushort)b0[g]));
      w1[g] = ee * (bf2f((ushort)a0[4 + g]) + bf2f((ushort)b0[4 + g]));
      w2[g] = ee * (bf2f((ushort)a1[g])     + bf2f((ushort)b1[g]));
      w3[g] = ee * (bf2f((ushort)a1[4 + g]) + bf2f((ushort)b1[4 + g]));
    }
    *(f32x4*)&plds[wv][jj][ds * 16]      = w0;
    *(f32x4*)&plds[wv][jj][ds * 16 + 4]  = w1;
    *(f32x4*)&plds[wv][jj][ds * 16 + 8]  = w2;
    *(f32x4*)&plds[wv][jj][ds * 16 + 12] = w3;
  }
  asm volatile("s_waitcnt lgkmcnt(0)" ::: "memory");
  __builtin_amdgcn_sched_barrier(0);

  float o = 0.f;
#pragma unroll
  for (int q = 0; q < 16; ++q) o += plds[wv][q][lane];
  ao[(size_t)row * DIMC + h * HD + lane] = f2bf(o * inv);
}

// ---- proj split-K reduce: out = sum_z parts[z] + bias (fp32) ---------------
#define NR8 (M_ROWS * DIMC / 8)   // 201728
__global__ __launch_bounds__(256)
void reduce4_bias(const ushort* __restrict__ parts, const float* __restrict__ bias,
                  float* __restrict__ out) {
  int i = blockIdx.x * 256 + threadIdx.x;
  if (i >= NR8) return;
  const size_t slice = (size_t)M_ROWS * DIMC;
  float a[8];
#pragma unroll
  for (int e = 0; e < 8; ++e) a[e] = 0.f;
#pragma unroll
  for (int z = 0; z < 4; ++z) {
    s16x8 v = *(const s16x8*)(parts + z * slice + (size_t)i * 8);
#pragma unroll
    for (int e = 0; e < 8; ++e) a[e] += bf2f((ushort)v[e]);
  }
  const int col = (i * 8) & (DIMC - 1);
  f32x4 b0 = *(const f32x4*)(bias + col);
  f32x4 b1 = *(const f32x4*)(bias + col + 4);
  f32x4 o0 = {a[0] + b0.x, a[1] + b0.y, a[2] + b0.z, a[3] + b0.w};
  f32x4 o1 = {a[4] + b1.x, a[5] + b1.y, a[6] + b1.z, a[7] + b1.w};
  ((f32x4*)out)[2 * i]     = o0;
  ((f32x4*)out)[2 * i + 1] = o1;
}

// ----------------------------------------------------------------------------
extern "C" void kernel_launch(void* const* d_in, const int* in_sizes, int n_in,
                              void* d_out, int out_size, void* d_ws, size_t ws_size,
                              hipStream_t stream) {
  const float* x      = (const float*)d_in[0];
  const float* qkv_w  = (const float*)d_in[1];
  const float* proj_w = (const float*)d_in[2];
  const float* proj_b = (const float*)d_in[3];
  float* out = (float*)d_out;

  char* p = (char*)d_ws;
  ushort* x_bf    = (ushort*)p;  p += (size_t)M_PAD * DIMC * 2;
  ushort* qkvw_bf = (ushort*)p;  p += (size_t)3 * DIMC * DIMC * 2;
  ushort* projw_bf= (ushort*)p;  p += (size_t)DIMC * DIMC * 2;
  ushort* qkv_p   = (ushort*)p;  p += (size_t)2 * M_ROWS * 3 * DIMC * 2;
  ushort* ao_bf   = (ushort*)p;  p += (size_t)M_PAD * DIMC * 2;
  ushort* proj_p  = (ushort*)p;

  dim3 blk(256);

  {
    int total = NX + NQ + NP;
    cvt_all<<<dim3((total + 255) / 256), blk, 0, stream>>>(
        x, qkv_w, proj_w, x_bf, qkvw_bf, projw_bf);
  }

  // QKV GEMM: split-K=2, grid (7,48,2) = 672 blocks, bf16 partial slices
  gemm_bt_bf16<<<dim3(M_PAD / 128, (3 * DIMC) / 128, 2), blk, 0, stream>>>(
      x_bf, qkvw_bf, qkv_p, M_ROWS, 3 * DIMC, DIMC, DIMC / 2);

  // Local attention (+ qkv partial reduce) -> ao bf16
  int total_waves = B_SZ * HEADS * N_SEQ;  // 25216
  local_attn<<<dim3((total_waves + 3) / 4), blk, 0, stream>>>(
      qkv_p, qkv_p + (size_t)M_ROWS * 3 * DIMC, ao_bf);

  // Proj GEMM: split-K=4, grid (7,16,4) = 448 blocks, bf16 partial slices
  gemm_bt_bf16<<<dim3(M_PAD / 128, DIMC / 128, 4), blk, 0, stream>>>(
      ao_bf, projw_bf, proj_p, M_ROWS, DIMC, DIMC, DIMC / 4);

  // Reduce 4 proj partials + bias -> fp32 d_out
  reduce4_bias<<<dim3((NR8 + 255) / 256), blk, 0, stream>>>(proj_p, proj_b, out);
}